// Round 17
// baseline (1091.612 us; speedup 1.0000x reference)
//
#include <hip/hip_runtime.h>

typedef float  f32x4  __attribute__((ext_vector_type(4)));
typedef __bf16 bf16x8 __attribute__((ext_vector_type(8)));

#define NB 64
#define NT 512
#define ND 256
#define NH 256
#define NROW (NB*NT)   // 32768

// ws ushort offsets
#define OFF_WIH 0
#define OFF_WHH 393216
#define OFF_WGT 786432          // [l][512][512]: rows 0-255 Wg, 256-511 Wt
#define OFF_WU  1310720
#define W_TOTAL 1441792
#define OFF_GI   (W_TOTAL)                  // [512][64][768] bf16 t-major (gi0 -> gi1 in place)
#define OFF_OUT0 (OFF_GI + 512*64*768)      // [64][512][256] bf16 (chain0 h)
#define OFF_OUT1 (OFF_OUT0 + NROW*256)      // [64][512][256] bf16 (chain1 h; aliases xin early)
#define OFF_FLAG (OFF_OUT1 + NROW*256)
// flags layout (ints, 32-int = 128B padded slots):
//   prog0[q] @ q*32            (q=0..31)
//   prog1[q] @ 1024 + q*32
//   bd[B]    @ 2048 + B*32     (B=0..31)
//   lay1 task counter @ 3072
#define FLAG_INTS 3073

#define NW 192   // lay0 worker WGs (strided tasks)

__device__ inline unsigned short f2bu(float f){
  unsigned int u = __builtin_bit_cast(unsigned int, f);
  unsigned int r = u + 0x7fffu + ((u >> 16) & 1u);
  return (unsigned short)(r >> 16);
}
__device__ inline float bf2f(unsigned short u){
  unsigned int v = ((unsigned int)u) << 16;
  return __builtin_bit_cast(float, v);
}
__device__ inline float sigm(float x){ return 1.0f / (1.0f + __expf(-x)); }
__device__ inline float tanhf_(float x){ return 1.0f - 2.0f / (__expf(2.0f * x) + 1.0f); }

#define MFMA(a,b,c) __builtin_amdgcn_mfma_f32_16x16x32_bf16((a),(b),(c),0,0,0)

__device__ inline void gload_lds16(const void* g, void* l){
  __builtin_amdgcn_global_load_lds(
    (const __attribute__((address_space(1))) unsigned int*)g,
    (__attribute__((address_space(3))) unsigned int*)l, 16, 0, 0);
}
__device__ inline bf16x8 ldG(const unsigned short* p){
  return *reinterpret_cast<const bf16x8*>(p);
}
template<int SLP>
__device__ inline void spin_ge(int* p, int tgt){
  while (__hip_atomic_load(p, __ATOMIC_RELAXED, __HIP_MEMORY_SCOPE_AGENT) < tgt)
    __builtin_amdgcn_s_sleep(SLP);
}

// ---------------- weight / input packing ----------------
__global__ void cvt_weights(const float* __restrict__ Wih, const float* __restrict__ Whh,
                            const float* __restrict__ Wg,  const float* __restrict__ Wt,
                            const float* __restrict__ Wu,  unsigned short* __restrict__ ws){
  int i = blockIdx.x * blockDim.x + threadIdx.x;
  if (i < OFF_WHH) {
    ws[i] = f2bu(Wih[i]);
  } else if (i < OFF_WGT) {
    ws[i] = f2bu(Whh[i - OFF_WHH]);
  } else if (i < OFF_WU) {
    int j = i - OFF_WGT;
    int l = j >> 18; int r = (j >> 9) & 511; int k = j & 511;
    float v = (r < 256) ? Wg[(l * 256 + r) * 512 + k]
                        : Wt[(l * 256 + (r - 256)) * 512 + k];
    ws[i] = f2bu(v);
  } else if (i < W_TOTAL) {
    ws[i] = f2bu(Wu[i - OFF_WU]);
  }
}

__global__ void pack_x(const float* __restrict__ x, unsigned short* __restrict__ xin){
  size_t i = ((size_t)blockIdx.x * blockDim.x + threadIdx.x) * 4;
  float4 v = *reinterpret_cast<const float4*>(x + i);
  ushort4 u; u.x = f2bu(v.x); u.y = f2bu(v.y); u.z = f2bu(v.z); u.w = f2bu(v.w);
  *reinterpret_cast<ushort4*>(xin + i) = u;
}

// ---------------- GI0 = x @ Wih0^T + (bih [+ bhh for r,z]) ----------------
__global__ __launch_bounds__(1024) void gi_gemm(
    const unsigned short* __restrict__ xin,  // [NROW][256] bf16 (b-major)
    const unsigned short* __restrict__ wih,  // [768][256]
    const float* __restrict__ bih, const float* __restrict__ bhh,
    unsigned short* __restrict__ gi)         // [512][64][768] t-major
{
  __shared__ alignas(16) unsigned short sA[64 * 256];
  const int tid = threadIdx.x, blk = blockIdx.x;
  const int ln = tid & 63, wv = tid >> 6, m = ln & 15, lg = ln >> 4;
  {
    const char* src = (const char*)(xin + (size_t)blk * 64 * 256);
    #pragma unroll
    for (int i = 0; i < 2; ++i){
      int o = tid * 16 + i * 16384;
      int r = o >> 9, wb = o & 511;
      gload_lds16(src + (size_t)r * 512 + (wb ^ ((r & 7) << 4)), (char*)sA + o);
    }
  }
  __syncthreads();
  f32x4 acc[3][4] = {};
  #pragma unroll
  for (int kc = 0; kc < 8; ++kc){
    int kk = kc * 32 + lg * 8;
    bf16x8 a[4];
    #pragma unroll
    for (int mt = 0; mt < 4; ++mt){
      int row = mt * 16 + m;
      a[mt] = *(const bf16x8*)((const char*)sA + row * 512 + ((kk * 2) ^ ((row & 7) << 4)));
    }
    #pragma unroll
    for (int g = 0; g < 3; ++g){
      bf16x8 b = ldG(wih + (size_t)(g * 256 + wv * 16 + m) * 256 + kk);
      #pragma unroll
      for (int mt = 0; mt < 4; ++mt) acc[g][mt] = MFMA(a[mt], b, acc[g][mt]);
    }
  }
  const int c = wv * 16 + m;
  #pragma unroll
  for (int g = 0; g < 3; ++g){
    float bias = bih[g * 256 + c] + (g < 2 ? bhh[g * 256 + c] : 0.f);
    #pragma unroll
    for (int mt = 0; mt < 4; ++mt){
      #pragma unroll
      for (int j = 0; j < 4; ++j){
        int row = blk * 64 + mt * 16 + lg * 4 + j;
        int b = row >> 9, t = row & 511;
        gi[((size_t)t * 64 + b) * 768 + g * 256 + c] = f2bu(acc[g][mt][j] + bias);
      }
    }
  }
}

// ---------------- sequential GRU chain (device role) ----------------
// prog: padded slot (this chain's progress). bd: base of padded bd slots (chain1 only).
__device__ void chain_role(
    int grp, const unsigned short* __restrict__ gi, const unsigned short* __restrict__ whh,
    const float* __restrict__ bhh, unsigned short* __restrict__ outw,
    float* __restrict__ hfin, int* prog, int* bd, char* smem)
{
  __builtin_amdgcn_s_setprio(1);
  char* hAc = smem;                       // [2][2 rows x 512B] = 2048 B
  const int tid = threadIdx.x;
  const int ln  = tid & 63, wv = tid >> 6;
  const int m   = ln & 15;
  const int lg  = ln >> 4;

  f32x4 wf[3][2][8];
  #pragma unroll
  for (int g = 0; g < 3; ++g)
    #pragma unroll
    for (int s = 0; s < 2; ++s){
      const unsigned short* p = whh + (size_t)(g * 256 + wv * 32 + s * 16 + m) * 256;
      #pragma unroll
      for (int kc = 0; kc < 8; ++kc){
        wf[g][s][kc] = *reinterpret_cast<const f32x4*>(p + kc * 32 + lg * 8);
        asm volatile("" : "+v"(wf[g][s][kc]));
      }
    }

  const int bb   = lg & 1;
  const int su   = lg >> 1;
  const int wcol = wv * 32 + su * 16 + m;
  const int brow = grp * 2 + bb;
  const float bNv = bhh[512 + wcol];

  const int arow  = m & 1;
  const int arows = arow << 4;
  const int rbase = arow * 512;
  const int wbyte = bb * 512 + ((wcol * 2) ^ (bb << 4));

  const unsigned short* gbase = gi + (size_t)brow * 768 + wcol;
  unsigned short* op = outw + (size_t)brow * NT * 256 + wcol;

  if (tid < 256){
    ((unsigned int*)hAc)[tid] = 0;
    ((unsigned int*)(hAc + 1024))[tid] = 0;
  }
  // chain1: gate GI1 blocks 0,1 before initial preload
  if (bd){
    if (tid == 0){ spin_ge<8>(&bd[0], 16); spin_ge<8>(&bd[32], 16); __threadfence(); }
    __syncthreads();
    (void)__hip_atomic_load(&bd[0], __ATOMIC_ACQUIRE, __HIP_MEMORY_SCOPE_AGENT);
  }
  unsigned int gAr = gbase[0], gAz = gbase[256], gAn = gbase[512];
  unsigned int gBr = gbase[49152], gBz = gbase[49152 + 256], gBn = gbase[49152 + 512];
  float h = 0.f;
  __syncthreads();

  auto body = [&](int t, int curo, unsigned int& GR, unsigned int& GZ, unsigned int& GN){
    float xr = bf2f((unsigned short)GR);
    float xz = bf2f((unsigned short)GZ);
    float xn = bf2f((unsigned short)GN);
    if (t + 2 < NT){
      const unsigned short* gp = gbase + (size_t)(t + 2) * 49152;
      GR = gp[0]; GZ = gp[256]; GN = gp[512];
    }
    f32x4 a00{}, a01{}, a10{}, a11{}, a20{}, a21{};
    #pragma unroll
    for (int kc = 0; kc < 8; ++kc){
      int kb = kc * 64 + lg * 16;
      bf16x8 hv = *(const bf16x8*)(hAc + curo + rbase + (kb ^ arows));
      a00 = MFMA(hv, __builtin_bit_cast(bf16x8, wf[0][0][kc]), a00);
      a01 = MFMA(hv, __builtin_bit_cast(bf16x8, wf[0][1][kc]), a01);
      a10 = MFMA(hv, __builtin_bit_cast(bf16x8, wf[1][0][kc]), a10);
      a11 = MFMA(hv, __builtin_bit_cast(bf16x8, wf[1][1][kc]), a11);
      a20 = MFMA(hv, __builtin_bit_cast(bf16x8, wf[2][0][kc]), a20);
      a21 = MFMA(hv, __builtin_bit_cast(bf16x8, wf[2][1][kc]), a21);
    }
    float aR = su ? (bb ? a01[1] : a01[0]) : (bb ? a00[1] : a00[0]);
    float aZ = su ? (bb ? a11[1] : a11[0]) : (bb ? a10[1] : a10[0]);
    float aN = su ? (bb ? a21[1] : a21[0]) : (bb ? a20[1] : a20[0]);
    float R = sigm(aR + xr);
    float Z = sigm(aZ + xz);
    float N = tanhf_(xn + R * (aN + bNv));
    h = N + Z * (h - N);
    unsigned short hb = f2bu(h);
    *(unsigned short*)(hAc + (curo ^ 1024) + wbyte) = hb;
    op[t * 256] = hb;
    asm volatile("s_waitcnt lgkmcnt(0)" ::: "memory");
    __builtin_amdgcn_sched_barrier(0);
    __builtin_amdgcn_s_barrier();
    __builtin_amdgcn_sched_barrier(0);
  };

  for (int tp = 0; tp < NT; tp += 2){
    if ((tp & 15) == 0){
      if (tp > 0){
        __syncthreads();    // drain outw stores of all waves
        if (tid == 0){
          __threadfence();
          __hip_atomic_store(prog, tp, __ATOMIC_RELEASE, __HIP_MEMORY_SCOPE_AGENT);
        }
      }
      if (bd){
        int B1 = (tp >> 4) + 1;
        if (B1 < 32){
          if (tid == 0){ spin_ge<8>(&bd[B1 * 32], 16); __threadfence(); }
          __syncthreads();
          (void)__hip_atomic_load(&bd[B1 * 32], __ATOMIC_ACQUIRE, __HIP_MEMORY_SCOPE_AGENT);
        }
      }
    }
    body(tp,     0,    gAr, gAz, gAn);
    body(tp + 1, 1024, gBr, gBz, gBn);
  }
  __syncthreads();
  if (tid == 0){
    __threadfence();
    __hip_atomic_store(prog, NT, __ATOMIC_RELEASE, __HIP_MEMORY_SCOPE_AGENT);
  }
  hfin[(size_t)brow * 256 + wcol] = h;
  __builtin_amdgcn_s_setprio(0);
  __syncthreads();
}

// ---------------- one refinement task (M=64 x one t), A-fragment reuse ----------------
template<int LAY>
__device__ void refine_task(
    int t, unsigned short* __restrict__ gi, const unsigned short* __restrict__ src0,
    const unsigned short* __restrict__ wsb,
    const float* __restrict__ bih, const float* __restrict__ bhh,
    const float* __restrict__ bg, const float* __restrict__ bt, const float* __restrict__ bu,
    float* __restrict__ o, int* flags, char* smem)
{
  const int tid = threadIdx.x;
  const int ln = tid & 63, wv = tid >> 6, m = ln & 15, lg = ln >> 4;

  auto ldA = [&](int row, int kbyte) -> bf16x8 {
    return *(const bf16x8*)(smem + row * 1024 + (kbyte ^ ((row & 7) << 4)));
  };

  #pragma unroll
  for (int q = 0; q < 8; ++q){
    int ofs = tid * 16 + q * 8192;
    int r = ofs >> 10, wb = ofs & 1023;
    int wb2 = (wb ^ ((r & 7) << 4)) & 511;   // out and rh halves read the same source
    gload_lds16((const char*)(src0 + ((size_t)r * NT + t) * 256) + wb2, smem + ofs);
  }
  __syncthreads();

  const unsigned short* wgt = wsb + OFF_WGT + (size_t)LAY * 512 * 512;
  const unsigned short* wu  = wsb + OFF_WU  + (size_t)LAY * 256 * 256;
  const float* bgp = bg + LAY * 256;
  const float* btp = bt + LAY * 256;
  const float* bup = bu + LAY * 256;

  for (int iter = 0; iter < 3; ++iter){
    float oo0[4][4], oo1[4][4];
    {
      f32x4 ag0[4] = {}, at0[4] = {}, ag1[4] = {}, at1[4] = {};
      #pragma unroll 2
      for (int kc = 0; kc < 16; ++kc){
        int kk = kc * 32 + lg * 8;
        bf16x8 A[4];
        #pragma unroll
        for (int mt = 0; mt < 4; ++mt) A[mt] = ldA(mt * 16 + m, kk * 2);
        bf16x8 Bg0 = ldG(wgt + (size_t)(      wv * 32 + m) * 512 + kk);
        bf16x8 Bt0 = ldG(wgt + (size_t)(256 + wv * 32 + m) * 512 + kk);
        bf16x8 Bg1 = ldG(wgt + (size_t)(      wv * 32 + 16 + m) * 512 + kk);
        bf16x8 Bt1 = ldG(wgt + (size_t)(256 + wv * 32 + 16 + m) * 512 + kk);
        #pragma unroll
        for (int mt = 0; mt < 4; ++mt){
          ag0[mt] = MFMA(A[mt], Bg0, ag0[mt]);
          at0[mt] = MFMA(A[mt], Bt0, at0[mt]);
          ag1[mt] = MFMA(A[mt], Bg1, ag1[mt]);
          at1[mt] = MFMA(A[mt], Bt1, at1[mt]);
        }
      }
      int c0 = wv * 32 + m, c1 = wv * 32 + 16 + m;
      float bg0 = bgp[c0], bt0 = btp[c0], bg1 = bgp[c1], bt1 = btp[c1];
      #pragma unroll
      for (int mt = 0; mt < 4; ++mt)
        #pragma unroll
        for (int j = 0; j < 4; ++j){
          int row = mt * 16 + lg * 4 + j;
          float old0 = bf2f(*(unsigned short*)(smem + row * 1024 + ((c0 * 2) ^ ((row & 7) << 4))));
          float old1 = bf2f(*(unsigned short*)(smem + row * 1024 + ((c1 * 2) ^ ((row & 7) << 4))));
          float g0 = sigm(ag0[mt][j] + bg0);
          float r0 = tanhf_(at0[mt][j] + bt0);
          float g1 = sigm(ag1[mt][j] + bg1);
          float r1 = tanhf_(at1[mt][j] + bt1);
          oo0[mt][j] = g0 * r0 + (1.f - g0) * old0;
          oo1[mt][j] = g1 * r1 + (1.f - g1) * old1;
        }
    }
    __syncthreads();   // all GEMM1 reads of LDS complete
    if (iter == 2 && LAY == 1){
      #pragma unroll
      for (int mt = 0; mt < 4; ++mt)
        #pragma unroll
        for (int j = 0; j < 4; ++j){
          int b = mt * 16 + lg * 4 + j;
          o[((size_t)b * NT + t) * 256 + wv * 32 + m]      = oo0[mt][j];
          o[((size_t)b * NT + t) * 256 + wv * 32 + 16 + m] = oo1[mt][j];
        }
    } else {
      #pragma unroll
      for (int mt = 0; mt < 4; ++mt)
        #pragma unroll
        for (int j = 0; j < 4; ++j){
          int row = mt * 16 + lg * 4 + j;
          int c0 = wv * 32 + m, c1 = wv * 32 + 16 + m;
          *(unsigned short*)(smem + row * 1024 + ((c0 * 2) ^ ((row & 7) << 4))) = f2bu(oo0[mt][j]);
          *(unsigned short*)(smem + row * 1024 + ((c1 * 2) ^ ((row & 7) << 4))) = f2bu(oo1[mt][j]);
        }
      __syncthreads();
      if (iter < 2){
        f32x4 au0[4] = {}, au1[4] = {};
        #pragma unroll 2
        for (int kc = 0; kc < 8; ++kc){
          int kk = kc * 32 + lg * 8;
          bf16x8 A[4];
          #pragma unroll
          for (int mt = 0; mt < 4; ++mt) A[mt] = ldA(mt * 16 + m, kk * 2);
          bf16x8 Bu0 = ldG(wu + (size_t)(wv * 32 + m) * 256 + kk);
          bf16x8 Bu1 = ldG(wu + (size_t)(wv * 32 + 16 + m) * 256 + kk);
          #pragma unroll
          for (int mt = 0; mt < 4; ++mt){
            au0[mt] = MFMA(A[mt], Bu0, au0[mt]);
            au1[mt] = MFMA(A[mt], Bu1, au1[mt]);
          }
        }
        int c0 = wv * 32 + m, c1 = wv * 32 + 16 + m;
        float bu0 = bup[c0], bu1 = bup[c1];
        #pragma unroll
        for (int mt = 0; mt < 4; ++mt)
          #pragma unroll
          for (int j = 0; j < 4; ++j){
            int row = mt * 16 + lg * 4 + j;
            *(unsigned short*)(smem + row * 1024 + (((512 + c0 * 2)) ^ ((row & 7) << 4)))
                = f2bu(tanhf_(au0[mt][j] + bu0));
            *(unsigned short*)(smem + row * 1024 + (((512 + c1 * 2)) ^ ((row & 7) << 4)))
                = f2bu(tanhf_(au1[mt][j] + bu1));
          }
        __syncthreads();
      }
    }
  }
  if (LAY == 0){
    // GI1[t] = refined_out @ Wih1^T + ..., q-tiles in pairs (A reused)
    const unsigned short* wih1 = wsb + OFF_WIH + (size_t)768 * 256;
    #pragma unroll
    for (int qp = 0; qp < 3; ++qp){
      int cg0 = (wv + 8 * (2 * qp)) * 16 + m;
      int cg1 = (wv + 8 * (2 * qp + 1)) * 16 + m;
      f32x4 acc0[4] = {}, acc1[4] = {};
      #pragma unroll
      for (int kc = 0; kc < 8; ++kc){
        int kk = kc * 32 + lg * 8;
        bf16x8 A[4];
        #pragma unroll
        for (int mt = 0; mt < 4; ++mt) A[mt] = ldA(mt * 16 + m, kk * 2);
        bf16x8 B0 = ldG(wih1 + (size_t)cg0 * 256 + kk);
        bf16x8 B1 = ldG(wih1 + (size_t)cg1 * 256 + kk);
        #pragma unroll
        for (int mt = 0; mt < 4; ++mt){
          acc0[mt] = MFMA(A[mt], B0, acc0[mt]);
          acc1[mt] = MFMA(A[mt], B1, acc1[mt]);
        }
      }
      float b0 = bih[768 + cg0] + (cg0 < 512 ? bhh[768 + cg0] : 0.f);
      float b1 = bih[768 + cg1] + (cg1 < 512 ? bhh[768 + cg1] : 0.f);
      #pragma unroll
      for (int mt = 0; mt < 4; ++mt)
        #pragma unroll
        for (int j = 0; j < 4; ++j){
          int b = mt * 16 + lg * 4 + j;
          gi[((size_t)t * 64 + b) * 768 + cg0] = f2bu(acc0[mt][j] + b0);
          gi[((size_t)t * 64 + b) * 768 + cg1] = f2bu(acc1[mt][j] + b1);
        }
    }
    __syncthreads();   // drains gi stores (vmcnt) for all waves
    if (tid == 0){
      __threadfence();
      __hip_atomic_fetch_add(&flags[2048 + (t >> 4) * 32], 1,
                             __ATOMIC_RELEASE, __HIP_MEMORY_SCOPE_AGENT);
    }
  } else {
    __syncthreads();   // LDS reusable next task
  }
}

// ---------------- mega kernel ----------------
// 0..NW-1 lay0 workers (strided) | NW..NW+31 chain0 | NW+32..NW+63 chain1
// afterwards ALL blocks drain the dynamic lay1 pool (counter flags[3072]).
__global__ __launch_bounds__(512, 2) void mega(
    unsigned short* __restrict__ gi, const unsigned short* __restrict__ wsb,
    const float* __restrict__ bih, const float* __restrict__ bhh,
    const float* __restrict__ bg, const float* __restrict__ bt, const float* __restrict__ bu,
    unsigned short* __restrict__ outw0, unsigned short* __restrict__ outw1,
    float* __restrict__ o, float* __restrict__ hf, int* flags)
{
  __shared__ char smem[65536];
  __shared__ int jslot;
  const int role = blockIdx.x;
  const int tid = threadIdx.x;

  if (role < NW){
    for (int t = role; t < 512; t += NW){
      if (tid == 0){
        for (int q = 0; q < 32; ++q) spin_ge<32>(&flags[q * 32], t + 1);
        __threadfence();
      }
      __syncthreads();
      (void)__hip_atomic_load(&flags[0], __ATOMIC_ACQUIRE, __HIP_MEMORY_SCOPE_AGENT);
      refine_task<0>(t, gi, outw0, wsb, bih, bhh, bg, bt, bu, o, flags, smem);
    }
  } else if (role < NW + 32){
    chain_role(role - NW, gi, wsb + OFF_WHH, bhh, outw0, hf,
               &flags[(role - NW) * 32], nullptr, smem);
  } else {
    chain_role(role - NW - 32, gi, wsb + OFF_WHH + 768 * 256, bhh + 768, outw1,
               hf + 64 * 256, &flags[1024 + (role - NW - 32) * 32], &flags[2048], smem);
  }

  // ---- dynamic lay1 pool ----
  for (;;){
    if (tid == 0)
      jslot = __hip_atomic_fetch_add(&flags[3072], 1, __ATOMIC_RELAXED, __HIP_MEMORY_SCOPE_AGENT);
    __syncthreads();
    int t = jslot;
    __syncthreads();
    if (t >= 512) break;
    if (tid == 0){
      for (int q = 0; q < 32; ++q) spin_ge<32>(&flags[1024 + q * 32], t + 1);
      __threadfence();
    }
    __syncthreads();
    (void)__hip_atomic_load(&flags[1024], __ATOMIC_ACQUIRE, __HIP_MEMORY_SCOPE_AGENT);
    refine_task<1>(t, gi, outw1, wsb, bih, bhh, bg, bt, bu, o, flags, smem);
  }
}

extern "C" void kernel_launch(void* const* d_in, const int* in_sizes, int n_in,
                              void* d_out, int out_size, void* d_ws, size_t ws_size,
                              hipStream_t stream) {
  const float* x   = (const float*)d_in[0];
  const float* Wih = (const float*)d_in[1];
  const float* bih = (const float*)d_in[2];
  const float* Whh = (const float*)d_in[3];
  const float* bhh = (const float*)d_in[4];
  const float* Wg  = (const float*)d_in[5];
  const float* bg  = (const float*)d_in[6];
  const float* Wt  = (const float*)d_in[7];
  const float* bt  = (const float*)d_in[8];
  const float* Wu  = (const float*)d_in[9];
  const float* bu  = (const float*)d_in[10];
  unsigned short* ws = (unsigned short*)d_ws;
  float* o  = (float*)d_out;
  float* hf = o + (size_t)NB * NT * NH;

  unsigned short* gi    = ws + OFF_GI;
  unsigned short* outw0 = ws + OFF_OUT0;
  unsigned short* outw1 = ws + OFF_OUT1;
  unsigned short* xin   = ws + OFF_OUT1;   // aliases outw1 (dead by the time chain1 writes)
  int* flags = (int*)(ws + OFF_FLAG);

  cvt_weights<<<W_TOTAL / 256, 256, 0, stream>>>(Wih, Whh, Wg, Wt, Wu, ws);
  pack_x<<<(NROW * 256 / 4) / 256, 256, 0, stream>>>(x, xin);
  gi_gemm<<<512, 1024, 0, stream>>>(xin, ws + OFF_WIH, bih, bhh, gi);
  (void)hipMemsetAsync(flags, 0, FLAG_INTS * sizeof(int), stream);
  mega<<<NW + 64, 512, 0, stream>>>(gi, ws, bih, bhh, bg, bt, bu, outw0, outw1, o, hf, flags);
}

// Round 18
// 977.835 us; speedup vs baseline: 1.1164x; 1.1164x over previous
//
#include <hip/hip_runtime.h>

typedef float  f32x4  __attribute__((ext_vector_type(4)));
typedef __bf16 bf16x8 __attribute__((ext_vector_type(8)));

#define NB 64
#define NT 512
#define ND 256
#define NH 256
#define NROW (NB*NT)   // 32768

// ws ushort offsets
#define OFF_WIH 0
#define OFF_WHH 393216
#define OFF_WGT 786432          // [l][512][512]: rows 0-255 Wg, 256-511 Wt
#define OFF_WU  1310720
#define W_TOTAL 1441792
#define OFF_GI   (W_TOTAL)                  // [512][64][768] bf16 t-major (gi0 -> gi1 in place)
#define OFF_OUT0 (OFF_GI + 512*64*768)      // [64][512][256] bf16 (chain0 h)
#define OFF_OUT1 (OFF_OUT0 + NROW*256)      // [64][512][256] bf16 (chain1 h; aliases xin early)
#define OFF_FLAG (OFF_OUT1 + NROW*256)      // int32: [0..31] prog0, [32..63] prog1, [64..95] bd

#define NW 192   // pool worker WGs (tasks strided by NW)

__device__ inline unsigned short f2bu(float f){
  unsigned int u = __builtin_bit_cast(unsigned int, f);
  unsigned int r = u + 0x7fffu + ((u >> 16) & 1u);
  return (unsigned short)(r >> 16);
}
__device__ inline float bf2f(unsigned short u){
  unsigned int v = ((unsigned int)u) << 16;
  return __builtin_bit_cast(float, v);
}
__device__ inline float sigm(float x){ return 1.0f / (1.0f + __expf(-x)); }
__device__ inline float tanhf_(float x){ return 1.0f - 2.0f / (__expf(2.0f * x) + 1.0f); }

#define MFMA(a,b,c) __builtin_amdgcn_mfma_f32_16x16x32_bf16((a),(b),(c),0,0,0)

__device__ inline void gload_lds16(const void* g, void* l){
  __builtin_amdgcn_global_load_lds(
    (const __attribute__((address_space(1))) unsigned int*)g,
    (__attribute__((address_space(3))) unsigned int*)l, 16, 0, 0);
}
__device__ inline bf16x8 ldG(const unsigned short* p){
  return *reinterpret_cast<const bf16x8*>(p);
}
template<int SLP>
__device__ inline void spin_ge(int* p, int tgt){
  while (__hip_atomic_load(p, __ATOMIC_RELAXED, __HIP_MEMORY_SCOPE_AGENT) < tgt)
    __builtin_amdgcn_s_sleep(SLP);
}

// ---------------- weight / input packing ----------------
__global__ void cvt_weights(const float* __restrict__ Wih, const float* __restrict__ Whh,
                            const float* __restrict__ Wg,  const float* __restrict__ Wt,
                            const float* __restrict__ Wu,  unsigned short* __restrict__ ws){
  int i = blockIdx.x * blockDim.x + threadIdx.x;
  if (i < OFF_WHH) {
    ws[i] = f2bu(Wih[i]);
  } else if (i < OFF_WGT) {
    ws[i] = f2bu(Whh[i - OFF_WHH]);
  } else if (i < OFF_WU) {
    int j = i - OFF_WGT;
    int l = j >> 18; int r = (j >> 9) & 511; int k = j & 511;
    float v = (r < 256) ? Wg[(l * 256 + r) * 512 + k]
                        : Wt[(l * 256 + (r - 256)) * 512 + k];
    ws[i] = f2bu(v);
  } else if (i < W_TOTAL) {
    ws[i] = f2bu(Wu[i - OFF_WU]);
  }
}

__global__ void pack_x(const float* __restrict__ x, unsigned short* __restrict__ xin){
  size_t i = ((size_t)blockIdx.x * blockDim.x + threadIdx.x) * 4;
  float4 v = *reinterpret_cast<const float4*>(x + i);
  ushort4 u; u.x = f2bu(v.x); u.y = f2bu(v.y); u.z = f2bu(v.z); u.w = f2bu(v.w);
  *reinterpret_cast<ushort4*>(xin + i) = u;
}

// ---------------- GI0 = x @ Wih0^T + (bih [+ bhh for r,z]) ----------------
__global__ __launch_bounds__(1024) void gi_gemm(
    const unsigned short* __restrict__ xin,  // [NROW][256] bf16 (b-major)
    const unsigned short* __restrict__ wih,  // [768][256]
    const float* __restrict__ bih, const float* __restrict__ bhh,
    unsigned short* __restrict__ gi)         // [512][64][768] t-major
{
  __shared__ alignas(16) unsigned short sA[64 * 256];
  const int tid = threadIdx.x, blk = blockIdx.x;
  const int ln = tid & 63, wv = tid >> 6, m = ln & 15, lg = ln >> 4;
  {
    const char* src = (const char*)(xin + (size_t)blk * 64 * 256);
    #pragma unroll
    for (int i = 0; i < 2; ++i){
      int o = tid * 16 + i * 16384;
      int r = o >> 9, wb = o & 511;
      gload_lds16(src + (size_t)r * 512 + (wb ^ ((r & 7) << 4)), (char*)sA + o);
    }
  }
  __syncthreads();
  f32x4 acc[3][4] = {};
  #pragma unroll
  for (int kc = 0; kc < 8; ++kc){
    int kk = kc * 32 + lg * 8;
    bf16x8 a[4];
    #pragma unroll
    for (int mt = 0; mt < 4; ++mt){
      int row = mt * 16 + m;
      a[mt] = *(const bf16x8*)((const char*)sA + row * 512 + ((kk * 2) ^ ((row & 7) << 4)));
    }
    #pragma unroll
    for (int g = 0; g < 3; ++g){
      bf16x8 b = ldG(wih + (size_t)(g * 256 + wv * 16 + m) * 256 + kk);
      #pragma unroll
      for (int mt = 0; mt < 4; ++mt) acc[g][mt] = MFMA(a[mt], b, acc[g][mt]);
    }
  }
  const int c = wv * 16 + m;
  #pragma unroll
  for (int g = 0; g < 3; ++g){
    float bias = bih[g * 256 + c] + (g < 2 ? bhh[g * 256 + c] : 0.f);
    #pragma unroll
    for (int mt = 0; mt < 4; ++mt){
      #pragma unroll
      for (int j = 0; j < 4; ++j){
        int row = blk * 64 + mt * 16 + lg * 4 + j;
        int b = row >> 9, t = row & 511;
        gi[((size_t)t * 64 + b) * 768 + g * 256 + c] = f2bu(acc[g][mt][j] + bias);
      }
    }
  }
}

// ---------------- sequential GRU chain (device role) ----------------
__device__ void chain_role(
    int grp, const unsigned short* __restrict__ gi, const unsigned short* __restrict__ whh,
    const float* __restrict__ bhh, unsigned short* __restrict__ outw,
    float* __restrict__ hfin, int* prog, int* bd, char* smem)
{
  __builtin_amdgcn_s_setprio(1);
  char* hAc = smem;                       // [2][2 rows x 512B] = 2048 B
  const int tid = threadIdx.x;
  const int ln  = tid & 63, wv = tid >> 6;
  const int m   = ln & 15;
  const int lg  = ln >> 4;

  f32x4 wf[3][2][8];
  #pragma unroll
  for (int g = 0; g < 3; ++g)
    #pragma unroll
    for (int s = 0; s < 2; ++s){
      const unsigned short* p = whh + (size_t)(g * 256 + wv * 32 + s * 16 + m) * 256;
      #pragma unroll
      for (int kc = 0; kc < 8; ++kc){
        wf[g][s][kc] = *reinterpret_cast<const f32x4*>(p + kc * 32 + lg * 8);
        asm volatile("" : "+v"(wf[g][s][kc]));
      }
    }

  const int bb   = lg & 1;
  const int su   = lg >> 1;
  const int wcol = wv * 32 + su * 16 + m;
  const int brow = grp * 2 + bb;
  const float bNv = bhh[512 + wcol];

  const int arow  = m & 1;
  const int arows = arow << 4;
  const int rbase = arow * 512;
  const int wbyte = bb * 512 + ((wcol * 2) ^ (bb << 4));

  const unsigned short* gbase = gi + (size_t)brow * 768 + wcol;
  unsigned short* op = outw + (size_t)brow * NT * 256 + wcol;

  if (tid < 256){
    ((unsigned int*)hAc)[tid] = 0;
    ((unsigned int*)(hAc + 1024))[tid] = 0;
  }
  // chain1: gate GI1 blocks 0,1 before initial preload
  if (bd){
    if (tid == 0){ spin_ge<8>(&bd[0], 16); spin_ge<8>(&bd[1], 16); __threadfence(); }
    __syncthreads();
    (void)__hip_atomic_load(&bd[0], __ATOMIC_ACQUIRE, __HIP_MEMORY_SCOPE_AGENT);
  }
  unsigned int gAr = gbase[0], gAz = gbase[256], gAn = gbase[512];
  unsigned int gBr = gbase[49152], gBz = gbase[49152 + 256], gBn = gbase[49152 + 512];
  float h = 0.f;
  __syncthreads();

  auto body = [&](int t, int curo, unsigned int& GR, unsigned int& GZ, unsigned int& GN){
    float xr = bf2f((unsigned short)GR);
    float xz = bf2f((unsigned short)GZ);
    float xn = bf2f((unsigned short)GN);
    if (t + 2 < NT){
      const unsigned short* gp = gbase + (size_t)(t + 2) * 49152;
      GR = gp[0]; GZ = gp[256]; GN = gp[512];
    }
    f32x4 a00{}, a01{}, a10{}, a11{}, a20{}, a21{};
    #pragma unroll
    for (int kc = 0; kc < 8; ++kc){
      int kb = kc * 64 + lg * 16;
      bf16x8 hv = *(const bf16x8*)(hAc + curo + rbase + (kb ^ arows));
      a00 = MFMA(hv, __builtin_bit_cast(bf16x8, wf[0][0][kc]), a00);
      a01 = MFMA(hv, __builtin_bit_cast(bf16x8, wf[0][1][kc]), a01);
      a10 = MFMA(hv, __builtin_bit_cast(bf16x8, wf[1][0][kc]), a10);
      a11 = MFMA(hv, __builtin_bit_cast(bf16x8, wf[1][1][kc]), a11);
      a20 = MFMA(hv, __builtin_bit_cast(bf16x8, wf[2][0][kc]), a20);
      a21 = MFMA(hv, __builtin_bit_cast(bf16x8, wf[2][1][kc]), a21);
    }
    float aR = su ? (bb ? a01[1] : a01[0]) : (bb ? a00[1] : a00[0]);
    float aZ = su ? (bb ? a11[1] : a11[0]) : (bb ? a10[1] : a10[0]);
    float aN = su ? (bb ? a21[1] : a21[0]) : (bb ? a20[1] : a20[0]);
    float R = sigm(aR + xr);
    float Z = sigm(aZ + xz);
    float N = tanhf_(xn + R * (aN + bNv));
    h = N + Z * (h - N);
    unsigned short hb = f2bu(h);
    *(unsigned short*)(hAc + (curo ^ 1024) + wbyte) = hb;
    op[t * 256] = hb;
    asm volatile("s_waitcnt lgkmcnt(0)" ::: "memory");
    __builtin_amdgcn_sched_barrier(0);
    __builtin_amdgcn_s_barrier();
    __builtin_amdgcn_sched_barrier(0);
  };

  for (int tp = 0; tp < NT; tp += 2){
    if ((tp & 15) == 0){
      if (tp > 0){
        __syncthreads();    // drain outw stores of all waves
        if (tid == 0){
          __threadfence();
          __hip_atomic_store(prog, tp, __ATOMIC_RELEASE, __HIP_MEMORY_SCOPE_AGENT);
        }
      }
      if (bd){
        int B1 = (tp >> 4) + 1;
        if (B1 < 32){
          if (tid == 0){ spin_ge<8>(&bd[B1], 16); __threadfence(); }
          __syncthreads();
          (void)__hip_atomic_load(&bd[B1], __ATOMIC_ACQUIRE, __HIP_MEMORY_SCOPE_AGENT);
        }
      }
    }
    body(tp,     0,    gAr, gAz, gAn);
    body(tp + 1, 1024, gBr, gBz, gBn);
  }
  __syncthreads();
  if (tid == 0){
    __threadfence();
    __hip_atomic_store(prog, NT, __ATOMIC_RELEASE, __HIP_MEMORY_SCOPE_AGENT);
  }
  hfin[(size_t)brow * 256 + wcol] = h;
}

// ---------------- refinement worker (pool; task i = (lay,t), M=64) ----------------
// A-fragment reuse: each ldA feeds all B-columns of the phase (halves LDS reads).
__device__ void worker_role(
    int w, unsigned short* __restrict__ gi,
    const unsigned short* __restrict__ outw0, const unsigned short* __restrict__ outw1,
    const unsigned short* __restrict__ wsb,
    const float* __restrict__ bih, const float* __restrict__ bhh,
    const float* __restrict__ bg, const float* __restrict__ bt, const float* __restrict__ bu,
    float* __restrict__ o, int* flags, char* smem)
{
  const int tid = threadIdx.x;
  const int ln = tid & 63, wv = tid >> 6, m = ln & 15, lg = ln >> 4;

  auto ldA = [&](int row, int kbyte) -> bf16x8 {
    return *(const bf16x8*)(smem + row * 1024 + (kbyte ^ ((row & 7) << 4)));
  };

  for (int i = w; i < 1024; i += NW){
    const int lay = i >> 9, t = i & 511;
    int* prog = &flags[lay * 32];
    if (tid == 0){
      for (int q = 0; q < 32; ++q) spin_ge<32>(&prog[q], t + 1);
      __threadfence();
    }
    __syncthreads();
    (void)__hip_atomic_load(&prog[0], __ATOMIC_ACQUIRE, __HIP_MEMORY_SCOPE_AGENT);

    const unsigned short* src0 = lay ? outw1 : outw0;
    #pragma unroll
    for (int q = 0; q < 8; ++q){
      int ofs = tid * 16 + q * 8192;
      int r = ofs >> 10, wb = ofs & 1023;
      int wb2 = (wb ^ ((r & 7) << 4)) & 511;   // out and rh halves read the same source
      gload_lds16((const char*)(src0 + ((size_t)r * NT + t) * 256) + wb2, smem + ofs);
    }
    __syncthreads();

    const unsigned short* wgt = wsb + OFF_WGT + (size_t)lay * 512 * 512;
    const unsigned short* wu  = wsb + OFF_WU  + (size_t)lay * 256 * 256;
    const float* bgp = bg + lay * 256;
    const float* btp = bt + lay * 256;
    const float* bup = bu + lay * 256;

    for (int iter = 0; iter < 3; ++iter){
      float oo0[4][4], oo1[4][4];
      // ---- GEMM1, both col-subtiles in one pass (A read once per kc) ----
      {
        f32x4 ag0[4] = {}, at0[4] = {}, ag1[4] = {}, at1[4] = {};
        #pragma unroll 2
        for (int kc = 0; kc < 16; ++kc){
          int kk = kc * 32 + lg * 8;
          bf16x8 A[4];
          #pragma unroll
          for (int mt = 0; mt < 4; ++mt) A[mt] = ldA(mt * 16 + m, kk * 2);
          bf16x8 Bg0 = ldG(wgt + (size_t)(      wv * 32 + m) * 512 + kk);
          bf16x8 Bt0 = ldG(wgt + (size_t)(256 + wv * 32 + m) * 512 + kk);
          bf16x8 Bg1 = ldG(wgt + (size_t)(      wv * 32 + 16 + m) * 512 + kk);
          bf16x8 Bt1 = ldG(wgt + (size_t)(256 + wv * 32 + 16 + m) * 512 + kk);
          #pragma unroll
          for (int mt = 0; mt < 4; ++mt){
            ag0[mt] = MFMA(A[mt], Bg0, ag0[mt]);
            at0[mt] = MFMA(A[mt], Bt0, at0[mt]);
            ag1[mt] = MFMA(A[mt], Bg1, ag1[mt]);
            at1[mt] = MFMA(A[mt], Bt1, at1[mt]);
          }
        }
        int c0 = wv * 32 + m, c1 = wv * 32 + 16 + m;
        float bg0 = bgp[c0], bt0 = btp[c0], bg1 = bgp[c1], bt1 = btp[c1];
        #pragma unroll
        for (int mt = 0; mt < 4; ++mt)
          #pragma unroll
          for (int j = 0; j < 4; ++j){
            int row = mt * 16 + lg * 4 + j;
            float old0 = bf2f(*(unsigned short*)(smem + row * 1024 + ((c0 * 2) ^ ((row & 7) << 4))));
            float old1 = bf2f(*(unsigned short*)(smem + row * 1024 + ((c1 * 2) ^ ((row & 7) << 4))));
            float g0 = sigm(ag0[mt][j] + bg0);
            float r0 = tanhf_(at0[mt][j] + bt0);
            float g1 = sigm(ag1[mt][j] + bg1);
            float r1 = tanhf_(at1[mt][j] + bt1);
            oo0[mt][j] = g0 * r0 + (1.f - g0) * old0;
            oo1[mt][j] = g1 * r1 + (1.f - g1) * old1;
          }
      }
      __syncthreads();   // all GEMM1 reads of LDS complete
      if (iter == 2 && lay == 1){
        // final: write f32 output rows directly
        #pragma unroll
        for (int mt = 0; mt < 4; ++mt)
          #pragma unroll
          for (int j = 0; j < 4; ++j){
            int b = mt * 16 + lg * 4 + j;
            o[((size_t)b * NT + t) * 256 + wv * 32 + m]      = oo0[mt][j];
            o[((size_t)b * NT + t) * 256 + wv * 32 + 16 + m] = oo1[mt][j];
          }
      } else {
        #pragma unroll
        for (int mt = 0; mt < 4; ++mt)
          #pragma unroll
          for (int j = 0; j < 4; ++j){
            int row = mt * 16 + lg * 4 + j;
            int c0 = wv * 32 + m, c1 = wv * 32 + 16 + m;
            *(unsigned short*)(smem + row * 1024 + ((c0 * 2) ^ ((row & 7) << 4))) = f2bu(oo0[mt][j]);
            *(unsigned short*)(smem + row * 1024 + ((c1 * 2) ^ ((row & 7) << 4))) = f2bu(oo1[mt][j]);
          }
        __syncthreads();
        if (iter < 2){
          // rh = tanh(out @ Wu^T + bu), both col-subtiles in one pass
          f32x4 au0[4] = {}, au1[4] = {};
          #pragma unroll 2
          for (int kc = 0; kc < 8; ++kc){
            int kk = kc * 32 + lg * 8;
            bf16x8 A[4];
            #pragma unroll
            for (int mt = 0; mt < 4; ++mt) A[mt] = ldA(mt * 16 + m, kk * 2);
            bf16x8 Bu0 = ldG(wu + (size_t)(wv * 32 + m) * 256 + kk);
            bf16x8 Bu1 = ldG(wu + (size_t)(wv * 32 + 16 + m) * 256 + kk);
            #pragma unroll
            for (int mt = 0; mt < 4; ++mt){
              au0[mt] = MFMA(A[mt], Bu0, au0[mt]);
              au1[mt] = MFMA(A[mt], Bu1, au1[mt]);
            }
          }
          int c0 = wv * 32 + m, c1 = wv * 32 + 16 + m;
          float bu0 = bup[c0], bu1 = bup[c1];
          #pragma unroll
          for (int mt = 0; mt < 4; ++mt)
            #pragma unroll
            for (int j = 0; j < 4; ++j){
              int row = mt * 16 + lg * 4 + j;
              *(unsigned short*)(smem + row * 1024 + (((512 + c0 * 2)) ^ ((row & 7) << 4)))
                  = f2bu(tanhf_(au0[mt][j] + bu0));
              *(unsigned short*)(smem + row * 1024 + (((512 + c1 * 2)) ^ ((row & 7) << 4)))
                  = f2bu(tanhf_(au1[mt][j] + bu1));
            }
          __syncthreads();
        }
      }
    }
    if (lay == 0){
      // GI1[t] = refined_out @ Wih1^T + ..., q-tiles in pairs (A reused)
      const unsigned short* wih1 = wsb + OFF_WIH + (size_t)768 * 256;
      #pragma unroll
      for (int qp = 0; qp < 3; ++qp){
        int cg0 = (wv + 8 * (2 * qp)) * 16 + m;
        int cg1 = (wv + 8 * (2 * qp + 1)) * 16 + m;
        f32x4 acc0[4] = {}, acc1[4] = {};
        #pragma unroll
        for (int kc = 0; kc < 8; ++kc){
          int kk = kc * 32 + lg * 8;
          bf16x8 A[4];
          #pragma unroll
          for (int mt = 0; mt < 4; ++mt) A[mt] = ldA(mt * 16 + m, kk * 2);
          bf16x8 B0 = ldG(wih1 + (size_t)cg0 * 256 + kk);
          bf16x8 B1 = ldG(wih1 + (size_t)cg1 * 256 + kk);
          #pragma unroll
          for (int mt = 0; mt < 4; ++mt){
            acc0[mt] = MFMA(A[mt], B0, acc0[mt]);
            acc1[mt] = MFMA(A[mt], B1, acc1[mt]);
          }
        }
        float b0 = bih[768 + cg0] + (cg0 < 512 ? bhh[768 + cg0] : 0.f);
        float b1 = bih[768 + cg1] + (cg1 < 512 ? bhh[768 + cg1] : 0.f);
        #pragma unroll
        for (int mt = 0; mt < 4; ++mt)
          #pragma unroll
          for (int j = 0; j < 4; ++j){
            int b = mt * 16 + lg * 4 + j;
            gi[((size_t)t * 64 + b) * 768 + cg0] = f2bu(acc0[mt][j] + b0);
            gi[((size_t)t * 64 + b) * 768 + cg1] = f2bu(acc1[mt][j] + b1);
          }
      }
      __syncthreads();   // drains gi stores (vmcnt) for all waves
      if (tid == 0){
        __threadfence();
        __hip_atomic_fetch_add(&flags[64 + (t >> 4)], 1, __ATOMIC_RELEASE, __HIP_MEMORY_SCOPE_AGENT);
      }
    } else {
      __syncthreads();   // LDS reusable next task
    }
  }
}

// ---------------- mega kernel: roles by blockIdx ----------------
// 0..NW-1 pool workers | NW..NW+31 chain0 | NW+32..NW+63 chain1
__global__ __launch_bounds__(512, 2) void mega(
    unsigned short* __restrict__ gi, const unsigned short* __restrict__ wsb,
    const float* __restrict__ bih, const float* __restrict__ bhh,
    const float* __restrict__ bg, const float* __restrict__ bt, const float* __restrict__ bu,
    unsigned short* __restrict__ outw0, unsigned short* __restrict__ outw1,
    float* __restrict__ o, float* __restrict__ hf, int* flags)
{
  __shared__ char smem[65536];
  const int role = blockIdx.x;
  if (role < NW){
    worker_role(role, gi, outw0, outw1, wsb, bih, bhh, bg, bt, bu, o, flags, smem);
  } else if (role < NW + 32){
    chain_role(role - NW, gi, wsb + OFF_WHH, bhh, outw0, hf,
               &flags[role - NW], nullptr, smem);
  } else {
    chain_role(role - NW - 32, gi, wsb + OFF_WHH + 768 * 256, bhh + 768, outw1,
               hf + 64 * 256, &flags[32 + (role - NW - 32)], &flags[64], smem);
  }
}

extern "C" void kernel_launch(void* const* d_in, const int* in_sizes, int n_in,
                              void* d_out, int out_size, void* d_ws, size_t ws_size,
                              hipStream_t stream) {
  const float* x   = (const float*)d_in[0];
  const float* Wih = (const float*)d_in[1];
  const float* bih = (const float*)d_in[2];
  const float* Whh = (const float*)d_in[3];
  const float* bhh = (const float*)d_in[4];
  const float* Wg  = (const float*)d_in[5];
  const float* bg  = (const float*)d_in[6];
  const float* Wt  = (const float*)d_in[7];
  const float* bt  = (const float*)d_in[8];
  const float* Wu  = (const float*)d_in[9];
  const float* bu  = (const float*)d_in[10];
  unsigned short* ws = (unsigned short*)d_ws;
  float* o  = (float*)d_out;
  float* hf = o + (size_t)NB * NT * NH;

  unsigned short* gi    = ws + OFF_GI;
  unsigned short* outw0 = ws + OFF_OUT0;
  unsigned short* outw1 = ws + OFF_OUT1;
  unsigned short* xin   = ws + OFF_OUT1;   // aliases outw1 (dead by the time chain1 writes)
  int* flags = (int*)(ws + OFF_FLAG);

  cvt_weights<<<W_TOTAL / 256, 256, 0, stream>>>(Wih, Whh, Wg, Wt, Wu, ws);
  pack_x<<<(NROW * 256 / 4) / 256, 256, 0, stream>>>(x, xin);
  gi_gemm<<<512, 1024, 0, stream>>>(xin, ws + OFF_WIH, bih, bhh, gi);
  (void)hipMemsetAsync(flags, 0, 96 * sizeof(int), stream);
  mega<<<NW + 64, 512, 0, stream>>>(gi, ws, bih, bhh, bg, bt, bu, outw0, outw1, o, hf, flags);
}